// Round 1
// baseline (668.762 us; speedup 1.0000x reference)
//
#include <hip/hip_runtime.h>

// OneToOneLinear: out[n] = prod_f sqrt(sigmoid(10*(x[n,f]*w[f]+b[f])))
// sqrt(sigmoid(z)) = rsqrt(1+exp(-z));  prod_f rsqrt(1+e_f) = rsqrt(prod_f (1+e_f))
// exp(-10(x*w+b)) = exp2(x*a + d), a = -10*w*log2(e), d = -10*b*log2(e).
// If prod(1+e) overflows fp32 -> inf -> v_rsq gives 0; true value < 1e-19,
// far below the 5.7e-10 absmax threshold. Safe.

typedef float vfloat4 __attribute__((ext_vector_type(4)));  // native vec for nontemporal builtin

__device__ __forceinline__ float exp2_hw(float x) {
    float r; asm("v_exp_f32 %0, %1" : "=v"(r) : "v"(x)); return r;   // 2^x, 1 instr
}
__device__ __forceinline__ float rsq_hw(float x) {
    float r; asm("v_rsq_f32 %0, %1" : "=v"(r) : "v"(x)); return r;   // 1/sqrt, 1 instr
}

// Butterfly product over the 16-lane group via ds_swizzle (BitMode:
// offset = xor_mask<<10 | or_mask<<5 | and_mask; and=0x1F keeps it within
// 32-lane halves, xor<16 never crosses the 16-group boundary).
template <int PAT>
__device__ __forceinline__ float bfly_mul(float p) {
    int q = __builtin_amdgcn_ds_swizzle(__builtin_bit_cast(int, p), PAT);
    return p * __builtin_bit_cast(float, q);
}
__device__ __forceinline__ float group16_prod(float p) {
    p = bfly_mul<0x041F>(p);   // xor 1
    p = bfly_mul<0x081F>(p);   // xor 2
    p = bfly_mul<0x101F>(p);   // xor 4
    p = bfly_mul<0x201F>(p);   // xor 8
    return p;
}

// Row = 64 floats = 16 float4. Lane i loads float4 #(base+i): one wave load
// = 64 x 16B = 1 KiB contiguous = 4 full rows. Lane's column group
// (threadIdx.x & 15) is loop-invariant -> (a,d) coeffs live in registers.
__global__ __launch_bounds__(256) void one2one_prod_kernel(
    const vfloat4* __restrict__ in4, // [N*16]
    const float*   __restrict__ w,   // [64]
    const float*   __restrict__ b,   // [64]
    float*         __restrict__ out, // [N]
    int total_f4)                    // N*16 = 2^25 (fits int; bytes = 2^29)
{
    const float C = -14.4269504088896340736f;  // -10 * log2(e)
    const int grp = threadIdx.x & 15;

    const vfloat4 wv = ((const vfloat4*)w)[grp];
    const vfloat4 bv = ((const vfloat4*)b)[grp];
    const float a0 = C * wv.x, a1 = C * wv.y, a2 = C * wv.z, a3 = C * wv.w;
    const float d0 = C * bv.x, d1 = C * bv.y, d2 = C * bv.z, d3 = C * bv.w;

    const int stride = gridDim.x * blockDim.x;
    int f = blockIdx.x * blockDim.x + threadIdx.x;

    // Unroll x2: two independent load->exp->product->butterfly chains.
    for (; f + stride < total_f4; f += 2 * stride) {
        vfloat4 x = __builtin_nontemporal_load(&in4[f]);
        vfloat4 y = __builtin_nontemporal_load(&in4[f + stride]);

        float px = (1.0f + exp2_hw(fmaf(x.x, a0, d0)))
                 * (1.0f + exp2_hw(fmaf(x.y, a1, d1)))
                 * (1.0f + exp2_hw(fmaf(x.z, a2, d2)))
                 * (1.0f + exp2_hw(fmaf(x.w, a3, d3)));
        float py = (1.0f + exp2_hw(fmaf(y.x, a0, d0)))
                 * (1.0f + exp2_hw(fmaf(y.y, a1, d1)))
                 * (1.0f + exp2_hw(fmaf(y.z, a2, d2)))
                 * (1.0f + exp2_hw(fmaf(y.w, a3, d3)));

        px = group16_prod(px);
        py = group16_prod(py);

        if (grp == 0) {
            out[f >> 4]            = rsq_hw(px);
            out[(f + stride) >> 4] = rsq_hw(py);
        }
    }
    if (f < total_f4) {  // tail (not taken for N=2^21: exactly 16 passes)
        vfloat4 x = __builtin_nontemporal_load(&in4[f]);
        float px = (1.0f + exp2_hw(fmaf(x.x, a0, d0)))
                 * (1.0f + exp2_hw(fmaf(x.y, a1, d1)))
                 * (1.0f + exp2_hw(fmaf(x.z, a2, d2)))
                 * (1.0f + exp2_hw(fmaf(x.w, a3, d3)));
        px = group16_prod(px);
        if (grp == 0) out[f >> 4] = rsq_hw(px);
    }
}

extern "C" void kernel_launch(void* const* d_in, const int* in_sizes, int n_in,
                              void* d_out, int out_size, void* d_ws, size_t ws_size,
                              hipStream_t stream) {
    const vfloat4* in4 = (const vfloat4*)d_in[0];  // [N,64] fp32
    const float*   w   = (const float*)d_in[1];    // [64]
    const float*   b   = (const float*)d_in[2];    // [64]
    float* out = (float*)d_out;                    // [N]

    const int total_f4 = in_sizes[0] / 4;          // N*16

    const int block = 256;
    const int grid  = 8192;  // 2M threads; 16 f4-passes -> 8 unrolled iters
    hipLaunchKernelGGL(one2one_prod_kernel, dim3(grid), dim3(block), 0, stream,
                       in4, w, b, out, total_f4);
}